// Round 3
// baseline (908.767 us; speedup 1.0000x reference)
//
#include <hip/hip_runtime.h>
#include <hip/hip_bf16.h>
#include <math.h>

// MoE FFN: N=8192 tokens, C=1024, H=4096, E=8, TOP_K=2.
// Round 3: BK=64 (half the barriers, 8 loads in flight per drain),
// XCD-affinity 1D grid decode (A-tile sharers land on one XCD),
// 128B-row XOR swizzle (conflict-free ds_read_b128).

#define N_TOK   8192
#define C_DIM   1024
#define H_DIM   4096
#define N_EXP   8
#define CAP     8192

typedef __bf16 bf16;
typedef bf16  bf16x8 __attribute__((ext_vector_type(8)));
typedef float f32x4  __attribute__((ext_vector_type(4)));

__device__ __forceinline__ void async_ld16(const void* g, void* l) {
    __builtin_amdgcn_global_load_lds(
        (const __attribute__((address_space(1))) void*)g,
        (__attribute__((address_space(3))) void*)l,
        16, 0, 0);
}

__device__ __forceinline__ float gelu_f(float v) {
    float u = v + 0.044715f * v * v * v;
    return 0.5f * v * (1.0f + tanhf(0.7978845608028654f * u));
}

// ---------------- fp32 -> bf16 ----------------
__global__ void cvt_k(const float* __restrict__ src, bf16* __restrict__ dst, int n8) {
    int i = blockIdx.x * blockDim.x + threadIdx.x;
    if (i >= n8) return;
    const float4* p = (const float4*)src + (size_t)i * 2;
    float4 a = p[0], b = p[1];
    bf16x8 v;
    v[0] = (bf16)a.x; v[1] = (bf16)a.y; v[2] = (bf16)a.z; v[3] = (bf16)a.w;
    v[4] = (bf16)b.x; v[5] = (bf16)b.y; v[6] = (bf16)b.z; v[7] = (bf16)b.w;
    *((bf16x8*)dst + i) = v;
}

// ---------------- router ----------------
__global__ __launch_bounds__(1024) void router_k(const float* __restrict__ x,
                                                 const float* __restrict__ rw,
                                                 int* __restrict__ counts,
                                                 int* __restrict__ tok,
                                                 float* __restrict__ gate) {
    __shared__ int lcnt[N_EXP];
    __shared__ int lbase[N_EXP];
    const int tid  = threadIdx.x;
    const int lane = tid & 63;
    const int wv   = tid >> 6;
    if (tid < N_EXP) lcnt[tid] = 0;
    __syncthreads();

    const int t = blockIdx.x * 16 + wv;

    float dot[N_EXP];
#pragma unroll
    for (int e = 0; e < N_EXP; ++e) dot[e] = 0.f;
    const float4* xr = (const float4*)(x + (size_t)t * C_DIM);
#pragma unroll
    for (int j = 0; j < 4; ++j) {
        float4 xv = xr[j * 64 + lane];
#pragma unroll
        for (int e = 0; e < N_EXP; ++e) {
            float4 w4 = ((const float4*)(rw + (size_t)e * C_DIM))[j * 64 + lane];
            dot[e] += xv.x * w4.x + xv.y * w4.y + xv.z * w4.z + xv.w * w4.w;
        }
    }
#pragma unroll
    for (int e = 0; e < N_EXP; ++e) {
#pragma unroll
        for (int o = 32; o > 0; o >>= 1) dot[e] += __shfl_xor(dot[e], o, 64);
    }

    int a = 0, b = 0, ra = 0, rb = 0;
    float g0 = 0.f, g1 = 0.f;
    if (lane == 0) {
        float m = dot[0];
#pragma unroll
        for (int e = 1; e < N_EXP; ++e) m = fmaxf(m, dot[e]);
        float p[N_EXP]; float s = 0.f;
#pragma unroll
        for (int e = 0; e < N_EXP; ++e) { p[e] = expf(dot[e] - m); s += p[e]; }
        a = 0;
#pragma unroll
        for (int e = 1; e < N_EXP; ++e) if (p[e] > p[a]) a = e;
        b = -1;
#pragma unroll
        for (int e = 0; e < N_EXP; ++e) if (e != a && (b < 0 || p[e] > p[b])) b = e;
        float pa = p[a] / s, pb = p[b] / s;
        float d = pa + pb + 1e-8f;
        g0 = pa / d; g1 = pb / d;
        ra = atomicAdd(&lcnt[a], 1);
        rb = atomicAdd(&lcnt[b], 1);
    }
    __syncthreads();
    if (tid < N_EXP) lbase[tid] = atomicAdd(&counts[tid], lcnt[tid]);
    __syncthreads();
    if (lane == 0) {
        int sa = lbase[a] + ra;
        int sb = lbase[b] + rb;
        tok[a * CAP + sa] = t;  gate[a * CAP + sa] = g0;
        tok[b * CAP + sb] = t;  gate[b * CAP + sb] = g1;
    }
}

__global__ void prefix_k(const int* __restrict__ counts, int* __restrict__ offs) {
    if (threadIdx.x == 0) {
        int s = 0;
        for (int e = 0; e < N_EXP; ++e) { offs[e] = s; s += counts[e]; }
    }
}

// Swizzle (BK=64, row stride 128 B = 32 banks):
//   LDS(row, c) holds global 8-elem chunk  gc = c ^ f(row),  f(row)=((row&1)<<2)|((row>>1)&3)
//   Staging lane l (rows l>>3 within a 16-row slab): dest = base + l*16 (DMA-compatible),
//     source chunk = (l&7) ^ ( (((l>>3)&1)<<2) | (l>>4) )
//   Read (m-row r=lane&15, k-group g=lane>>4, sub-step s): chunk = (s*4+g) ^ f(r)
//   => every 8 consecutive lanes of a ds_read_b128 cover all 32 banks exactly once.

// ---------------- fc1: h = gelu(x_gathered @ w1^T + b1) ----------------
__global__ __launch_bounds__(256) void fc1_k(const bf16* __restrict__ xb,
                                             const bf16* __restrict__ w1b,
                                             const float* __restrict__ b1,
                                             const int* __restrict__ counts,
                                             const int* __restrict__ offs,
                                             const int* __restrict__ tok,
                                             bf16* __restrict__ h) {
    // XCD-affinity decode: slot = bid&7 stays fixed for all 32 x-blocks of one (e,y)
    const int bid  = blockIdx.x;
    const int slot = bid & 7;
    const int inner = bid >> 3;
    const int xB   = inner & 31;          // 32 n-tiles
    const int yL   = inner >> 5;          // 0..63
    const int yG   = yL * 8 + slot;       // 0..511 interleaved mod 8
    const int e    = yG >> 6;
    const int m0   = (yG & 63) * 128;
    const int cnt  = counts[e];
    if (m0 >= cnt) return;
    const int n0   = xB * 128;
    const int off  = offs[e];

    __shared__ __align__(16) bf16 As[128][64];
    __shared__ __align__(16) bf16 Bs[128][64];

    const int tid  = threadIdx.x;
    const int lane = tid & 63;
    const int wv   = tid >> 6;
    const int wm   = wv & 1;
    const int wn   = wv >> 1;

    // staging: lane l covers row (wv*8 + (l>>3)) + p*32, chunk l&7 (swizzled source)
    const int swz  = (((lane >> 3) & 1) << 2) | (lane >> 4);
    const int scol = ((lane & 7) ^ swz) * 8;
    const int rbase = wv * 8 + (lane >> 3);

    const bf16* gA[4]; const bf16* gB[4];
#pragma unroll
    for (int p = 0; p < 4; ++p) {
        const int i = m0 + p * 32 + rbase;
        const int t = tok[e * CAP + (i < cnt ? i : cnt - 1)];
        gA[p] = xb + (size_t)t * C_DIM + scol;
        gB[p] = w1b + ((size_t)e * H_DIM + n0 + p * 32 + rbase) * C_DIM + scol;
    }
    char* ldsA = (char*)&As[0][0] + (size_t)(wv * 8) * 128 + (size_t)lane * 16;
    char* ldsB = (char*)&Bs[0][0] + (size_t)(wv * 8) * 128 + (size_t)lane * 16;

    f32x4 acc[4][4];
#pragma unroll
    for (int mi = 0; mi < 4; ++mi)
#pragma unroll
        for (int ni = 0; ni < 4; ++ni)
#pragma unroll
            for (int r = 0; r < 4; ++r) acc[mi][ni][r] = 0.f;

    const int r_ = lane & 15;
    const int g_ = lane >> 4;
    const int fr = ((r_ & 1) << 2) | ((r_ >> 1) & 3);
    const int col0 = ((g_)     ^ fr) * 8;
    const int col1 = ((4 + g_) ^ fr) * 8;

    for (int kt = 0; kt < C_DIM / 64; ++kt) {
        const int k0 = kt * 64;
#pragma unroll
        for (int p = 0; p < 4; ++p) {
            async_ld16(gA[p] + k0, ldsA + p * 4096);
            async_ld16(gB[p] + k0, ldsB + p * 4096);
        }
        __syncthreads();

#pragma unroll
        for (int s = 0; s < 2; ++s) {
            const int cc = s ? col1 : col0;
            bf16x8 af[4];
#pragma unroll
            for (int mi = 0; mi < 4; ++mi)
                af[mi] = *(const bf16x8*)&As[wm * 64 + mi * 16 + r_][cc];
#pragma unroll
            for (int ni = 0; ni < 4; ++ni) {
                bf16x8 bfr = *(const bf16x8*)&Bs[wn * 64 + ni * 16 + r_][cc];
#pragma unroll
                for (int mi = 0; mi < 4; ++mi)
                    acc[mi][ni] = __builtin_amdgcn_mfma_f32_16x16x32_bf16(af[mi], bfr, acc[mi][ni], 0, 0, 0);
            }
        }
        __syncthreads();
    }

    const int lg = lane >> 4, ln = lane & 15;
#pragma unroll
    for (int mi = 0; mi < 4; ++mi) {
#pragma unroll
        for (int r = 0; r < 4; ++r) {
            const int m = wm * 64 + mi * 16 + lg * 4 + r;
            if (m0 + m < cnt) {
                const size_t hrow = (size_t)(off + m0 + m) * H_DIM;
#pragma unroll
                for (int ni = 0; ni < 4; ++ni) {
                    const int n = n0 + wn * 64 + ni * 16 + ln;
                    float v = acc[mi][ni][r] + b1[(size_t)e * H_DIM + n];
                    h[hrow + n] = (bf16)gelu_f(v);
                }
            }
        }
    }
}

// ---------------- fc2: out += gate * (h @ w2^T + b2) ----------------
__global__ __launch_bounds__(256) void fc2_k(const bf16* __restrict__ h,
                                             const bf16* __restrict__ w2b,
                                             const float* __restrict__ b2,
                                             const int* __restrict__ counts,
                                             const int* __restrict__ offs,
                                             const int* __restrict__ tok,
                                             const float* __restrict__ gate,
                                             float* __restrict__ out) {
    const int bid  = blockIdx.x;
    const int slot = bid & 7;
    const int inner = bid >> 3;
    const int xB   = inner & 7;           // 8 n-tiles
    const int yL   = inner >> 3;          // 0..63
    const int yG   = yL * 8 + slot;
    const int e    = yG >> 6;
    const int m0   = (yG & 63) * 128;
    const int cnt  = counts[e];
    if (m0 >= cnt) return;
    const int n0   = xB * 128;
    const int off  = offs[e];

    __shared__ __align__(16) bf16 As[128][64];
    __shared__ __align__(16) bf16 Bs[128][64];

    const int tid  = threadIdx.x;
    const int lane = tid & 63;
    const int wv   = tid >> 6;
    const int wm   = wv & 1;
    const int wn   = wv >> 1;

    const int swz  = (((lane >> 3) & 1) << 2) | (lane >> 4);
    const int scol = ((lane & 7) ^ swz) * 8;
    const int rbase = wv * 8 + (lane >> 3);

    const bf16* gA[4]; const bf16* gB[4];
#pragma unroll
    for (int p = 0; p < 4; ++p) {
        const int i = m0 + p * 32 + rbase;
        gA[p] = h + (size_t)(off + (i < cnt ? i : cnt - 1)) * H_DIM + scol;
        gB[p] = w2b + ((size_t)e * C_DIM + n0 + p * 32 + rbase) * H_DIM + scol;
    }
    char* ldsA = (char*)&As[0][0] + (size_t)(wv * 8) * 128 + (size_t)lane * 16;
    char* ldsB = (char*)&Bs[0][0] + (size_t)(wv * 8) * 128 + (size_t)lane * 16;

    f32x4 acc[4][4];
#pragma unroll
    for (int mi = 0; mi < 4; ++mi)
#pragma unroll
        for (int ni = 0; ni < 4; ++ni)
#pragma unroll
            for (int r = 0; r < 4; ++r) acc[mi][ni][r] = 0.f;

    const int r_ = lane & 15;
    const int g_ = lane >> 4;
    const int fr = ((r_ & 1) << 2) | ((r_ >> 1) & 3);
    const int col0 = ((g_)     ^ fr) * 8;
    const int col1 = ((4 + g_) ^ fr) * 8;

    for (int kt = 0; kt < H_DIM / 64; ++kt) {
        const int k0 = kt * 64;
#pragma unroll
        for (int p = 0; p < 4; ++p) {
            async_ld16(gA[p] + k0, ldsA + p * 4096);
            async_ld16(gB[p] + k0, ldsB + p * 4096);
        }
        __syncthreads();

#pragma unroll
        for (int s = 0; s < 2; ++s) {
            const int cc = s ? col1 : col0;
            bf16x8 af[4];
#pragma unroll
            for (int mi = 0; mi < 4; ++mi)
                af[mi] = *(const bf16x8*)&As[wm * 64 + mi * 16 + r_][cc];
#pragma unroll
            for (int ni = 0; ni < 4; ++ni) {
                bf16x8 bfr = *(const bf16x8*)&Bs[wn * 64 + ni * 16 + r_][cc];
#pragma unroll
                for (int mi = 0; mi < 4; ++mi)
                    acc[mi][ni] = __builtin_amdgcn_mfma_f32_16x16x32_bf16(af[mi], bfr, acc[mi][ni], 0, 0, 0);
            }
        }
        __syncthreads();
    }

    const int lg = lane >> 4, ln = lane & 15;
#pragma unroll
    for (int mi = 0; mi < 4; ++mi) {
#pragma unroll
        for (int r = 0; r < 4; ++r) {
            const int m = wm * 64 + mi * 16 + lg * 4 + r;
            if (m0 + m < cnt) {
                const int   tk = tok[e * CAP + m0 + m];
                const float g  = gate[e * CAP + m0 + m];
#pragma unroll
                for (int ni = 0; ni < 4; ++ni) {
                    const int n = n0 + wn * 64 + ni * 16 + ln;
                    float v = (acc[mi][ni][r] + b2[(size_t)e * C_DIM + n]) * g;
                    atomicAdd(&out[(size_t)tk * C_DIM + n], v);
                }
            }
        }
    }
}

extern "C" void kernel_launch(void* const* d_in, const int* in_sizes, int n_in,
                              void* d_out, int out_size, void* d_ws, size_t ws_size,
                              hipStream_t stream) {
    const float* x  = (const float*)d_in[0];
    const float* rw = (const float*)d_in[1];
    const float* w1 = (const float*)d_in[2];
    const float* b1 = (const float*)d_in[3];
    const float* w2 = (const float*)d_in[4];
    const float* b2 = (const float*)d_in[5];
    float* out = (float*)d_out;

    char* ws = (char*)d_ws;
    size_t o = 0;
    bf16* xb     = (bf16*)(ws + o);  o += (size_t)N_TOK * C_DIM * sizeof(bf16);
    bf16* w1b    = (bf16*)(ws + o);  o += (size_t)N_EXP * H_DIM * C_DIM * sizeof(bf16);
    bf16* w2b    = (bf16*)(ws + o);  o += (size_t)N_EXP * C_DIM * H_DIM * sizeof(bf16);
    int*  tok    = (int*)(ws + o);   o += (size_t)N_EXP * CAP * sizeof(int);
    float* gate  = (float*)(ws + o); o += (size_t)N_EXP * CAP * sizeof(float);
    int*  counts = (int*)(ws + o);   o += 128;
    int*  offs   = (int*)(ws + o);   o += 128;
    bf16* h      = (bf16*)(ws + o);  o += (size_t)(2 * N_TOK) * H_DIM * sizeof(bf16);

    hipMemsetAsync(d_out, 0, (size_t)N_TOK * C_DIM * sizeof(float), stream);
    hipMemsetAsync(counts, 0, 128, stream);

    const int NW = N_EXP * H_DIM * C_DIM / 8;
    cvt_k<<<dim3((N_TOK * C_DIM / 8 + 255) / 256), 256, 0, stream>>>(x, xb, N_TOK * C_DIM / 8);
    cvt_k<<<dim3((NW + 255) / 256), 256, 0, stream>>>(w1, w1b, NW);
    cvt_k<<<dim3((NW + 255) / 256), 256, 0, stream>>>(w2, w2b, NW);
    router_k<<<dim3(N_TOK / 16), dim3(1024), 0, stream>>>(x, rw, counts, tok, gate);
    prefix_k<<<dim3(1), dim3(64), 0, stream>>>(counts, offs);
    fc1_k<<<dim3(32 * 64 * N_EXP), dim3(256), 0, stream>>>(xb, w1b, b1, counts, offs, tok, h);
    fc2_k<<<dim3(8 * 64 * N_EXP), dim3(256), 0, stream>>>(h, w2b, b2, counts, offs, tok, gate, out);
}